// Round 6
// baseline (311.251 us; speedup 1.0000x reference)
//
#include <hip/hip_runtime.h>

#define NN 20000
#define IN_DIM 256
#define HID 128
#define OUT_DIM 64
#define N_LAYERS 4
#define N_PATHS 8
#define PATH_LEN 8
#define N_TYPES 2

typedef __attribute__((ext_vector_type(8))) short bf16x8;
typedef __attribute__((ext_vector_type(4))) float f32x4;

__device__ __forceinline__ float bf2f(ushort u) {
    union { uint u; float f; } c; c.u = ((uint)u) << 16; return c.f;
}
__device__ __forceinline__ ushort f2bf(float f) {
    union { float f; uint u; } c; c.f = f;
    uint u = c.u;
    uint lsb = (u >> 16) & 1;
    u += 0x7fffu + lsb;          // round-to-nearest-even (inputs finite)
    return (ushort)(u >> 16);
}

// ---------------------------------------------------------------------------
// One-shot fp32 -> bf16 conversion of all weight matrices (quad-per-thread).
// ---------------------------------------------------------------------------
__global__ __launch_bounds__(256) void cvt_weights(
    const float* __restrict__ w_in, const float* __restrict__ w_layer,
    const float* __restrict__ w_out,
    ushort* __restrict__ o_in, ushort* __restrict__ o_layer,
    ushort* __restrict__ o_out)
{
    int i = blockIdx.x * 256 + threadIdx.x;
    const float* s; ushort* d; int off;
    if (i < 8192)        { s = w_in;    d = o_in;    off = i; }
    else if (i < 40960)  { s = w_layer; d = o_layer; off = i - 8192; }
    else if (i < 43008)  { s = w_out;   d = o_out;   off = i - 40960; }
    else return;
    float4 v = ((const float4*)s)[off];
    ushort4 o;
    o.x = f2bf(v.x); o.y = f2bf(v.y); o.z = f2bf(v.z); o.w = f2bf(v.w);
    ((ushort4*)d)[off] = o;
}

// ---------------------------------------------------------------------------
// bf16 MFMA GEMM (proven round-4): C = relu(A[M,K] @ W[N,K]^T + bias).
// BM=64, BK=64, 4 waves (2x2). LDS XOR-swizzle (T2). fc_in / fc_out only.
// EPI 0: bf16 out;  EPI 2: f32 out.
// ---------------------------------------------------------------------------
template <int N, int K, int EPI, bool AF32>
__global__ __launch_bounds__(256) void gemm_mfma(
    const void* __restrict__ Ap,
    const ushort* __restrict__ W,     // [N][K] bf16
    const float* __restrict__ bias,
    void* __restrict__ Cout,
    int M)
{
    constexpr int BM = 64, BK = 64;
    constexpr int NC = N / 32;

    __shared__ short As[BM * BK];
    __shared__ short Ws[N * BK];

    const int tid = threadIdx.x;
    const int lane = tid & 63;
    const int w = tid >> 6;
    const int wr = w >> 1, wc = w & 1;
    const int m0 = blockIdx.x * BM;
    const int l15 = lane & 15, l4 = lane >> 4;

    f32x4 acc[2][NC];
#pragma unroll
    for (int mr = 0; mr < 2; ++mr)
#pragma unroll
        for (int nc = 0; nc < NC; ++nc)
#pragma unroll
            for (int j = 0; j < 4; ++j) acc[mr][nc][j] = 0.f;

    for (int k0 = 0; k0 < K; k0 += BK) {
#pragma unroll
        for (int c = tid; c < BM * BK / 8; c += 256) {
            int r = c >> 3, kc = c & 7;
            int gr = m0 + r; if (gr >= M) gr = M - 1;
            bf16x8 v;
            if constexpr (AF32) {
                const float* Af = (const float*)Ap;
                float4 v0 = *(const float4*)(Af + (long)gr * K + k0 + kc * 8);
                float4 v1 = *(const float4*)(Af + (long)gr * K + k0 + kc * 8 + 4);
                v[0] = (short)f2bf(v0.x); v[1] = (short)f2bf(v0.y);
                v[2] = (short)f2bf(v0.z); v[3] = (short)f2bf(v0.w);
                v[4] = (short)f2bf(v1.x); v[5] = (short)f2bf(v1.y);
                v[6] = (short)f2bf(v1.z); v[7] = (short)f2bf(v1.w);
            } else {
                v = *(const bf16x8*)((const ushort*)Ap + (long)gr * K + k0 + kc * 8);
            }
            int di = (r * BK + kc * 8) ^ ((r & 7) << 3);
            *(bf16x8*)&As[di] = v;
        }
#pragma unroll
        for (int c = tid; c < N * BK / 8; c += 256) {
            int r = c >> 3, kc = c & 7;
            bf16x8 v = *(const bf16x8*)(W + (long)r * K + k0 + kc * 8);
            int di = (r * BK + kc * 8) ^ ((r & 7) << 3);
            *(bf16x8*)&Ws[di] = v;
        }
        __syncthreads();

#pragma unroll
        for (int ks = 0; ks < 2; ++ks) {
            bf16x8 av[2], bv[NC];
            const int kk = ks * 32 + l4 * 8;
#pragma unroll
            for (int mr = 0; mr < 2; ++mr) {
                int r = wr * 32 + mr * 16 + l15;
                av[mr] = *(const bf16x8*)&As[(r * BK + kk) ^ ((r & 7) << 3)];
            }
#pragma unroll
            for (int nc = 0; nc < NC; ++nc) {
                int r = wc * (N / 2) + nc * 16 + l15;
                bv[nc] = *(const bf16x8*)&Ws[(r * BK + kk) ^ ((r & 7) << 3)];
            }
#pragma unroll
            for (int mr = 0; mr < 2; ++mr)
#pragma unroll
                for (int nc = 0; nc < NC; ++nc)
                    acc[mr][nc] = __builtin_amdgcn_mfma_f32_16x16x32_bf16(
                        av[mr], bv[nc], acc[mr][nc], 0, 0, 0);
        }
        __syncthreads();
    }

#pragma unroll
    for (int mr = 0; mr < 2; ++mr) {
#pragma unroll
        for (int nc = 0; nc < NC; ++nc) {
            int gn = wc * (N / 2) + nc * 16 + l15;
#pragma unroll
            for (int j = 0; j < 4; ++j) {
                int gm = m0 + wr * 32 + mr * 16 + l4 * 4 + j;
                if (gm >= M) continue;
                float v = acc[mr][nc][j] + bias[gn];
                v = fmaxf(v, 0.f);
                if (EPI == 0) ((ushort*)Cout)[(long)gm * N + gn] = f2bf(v);
                else          ((float*)Cout)[(long)gm * N + gn] = v;
            }
        }
    }
}

// ---------------------------------------------------------------------------
// FUSED layer v2: 64-node tile, 512 threads (8 waves).
// Phase 0: stage 64x64 path indices into LDS (int4-coalesced).
// Phase 1: round-4 gather pattern -> swizzled LDS A-tile Pt[64][256] bf16.
//          thread = (group g=tid>>4 -> node, lane l16 -> channel quad);
//          2 h-half x 2 node-subset iterations; weights in static regs,
//          pre-scaled by 1/count_e; wave-uniform type branch.
// Phase 2: round-4 GEMM shape: 8 waves = 2 row-blocks x 4 col-blocks,
//          BK=64 W chunks (16 KB, overlays idxs), 8 MFMAs/wave/chunk.
// Epilogue: dst = 0.8*relu(acc) + 0.1*pre + 0.1*in0 (bf16).
// LDS: Pt 32K + (idxs|Ws) 16K = 48 KB -> 3 blocks/CU.
// ---------------------------------------------------------------------------
__global__ __launch_bounds__(512) void fused_layer(
    const uint* __restrict__ feats_u,   // [NN][64] (bf16x2)
    const int* __restrict__ paths,      // [P][NN][L]
    const int* __restrict__ ptypes,     // [P]
    const float* __restrict__ pw,       // [2][L][HID] f32
    const ushort* __restrict__ W,       // [HID][2*HID] bf16
    const ushort* __restrict__ pre,     // [NN][HID] bf16
    const ushort* __restrict__ in0,     // [NN][HID] bf16
    ushort* __restrict__ dst)           // [NN][HID] bf16
{
    __shared__ __align__(16) char smem[49152];
    short* Pt   = (short*)smem;             // [64*256] bf16, swizzled
    int*   idxs = (int*)(smem + 32768);     // [64][64]   (phase 0/1)
    short* Ws   = (short*)(smem + 32768);   // [128*64]   (phase 2, overlay)

    const int tid = threadIdx.x;
    const int nbase = blockIdx.x * 64;

    // ---- phase 0: stage path indices (int4-coalesced) ----
    {
        const int4* psrc = (const int4*)paths;
#pragma unroll
        for (int i = 0; i < 2; ++i) {
            int c = tid + i * 512;          // 0..1023
            int nd = c >> 4, q = c & 15;    // q = p*2 + half
            int p = q >> 1, half = q & 1;
            int n = nbase + nd; if (n >= NN) n = NN - 1;
            ((int4*)idxs)[c] = psrc[((long)p * NN + n) * 2 + half];
        }
    }
    __syncthreads();

    uint tmask = 0;
#pragma unroll
    for (int p = 0; p < N_PATHS; ++p) tmask |= (uint)(ptypes[p] != 0) << p;
    const int c1 = __popc(tmask), c0 = N_PATHS - c1;
    const float inv0 = c0 ? 1.f / (float)c0 : 0.f;
    const float inv1 = c1 ? 1.f / (float)c1 : 0.f;

    // ---- phase 1: gather into Pt ----
    {
        const int l16 = tid & 15;
        const int g = tid >> 4;             // 0..31

#define GATH_FMA(WV, ACC)                                                   \
        {                                                                   \
            int ia[8] = {i0.x, i0.y, i0.z, i0.w, i1.x, i1.y, i1.z, i1.w};   \
            _Pragma("unroll")                                               \
            for (int l = 0; l < 8; ++l) {                                   \
                uint2 v = *(const uint2*)(feats_u + (long)ia[l] * 64 + coff); \
                ACC.x += bf2f((ushort)(v.x & 0xffff)) * WV[l].x;            \
                ACC.y += bf2f((ushort)(v.x >> 16))    * WV[l].y;            \
                ACC.z += bf2f((ushort)(v.y & 0xffff)) * WV[l].z;            \
                ACC.w += bf2f((ushort)(v.y >> 16))    * WV[l].w;            \
            }                                                               \
        }

#pragma unroll
        for (int hh = 0; hh < 2; ++hh) {
            float4 wv0[PATH_LEN], wv1[PATH_LEN];
#pragma unroll
            for (int l = 0; l < PATH_LEN; ++l) {
                float4 t0 = *(const float4*)&pw[l * HID + hh * 64 + l16 * 4];
                float4 t1 = *(const float4*)&pw[(PATH_LEN + l) * HID + hh * 64 + l16 * 4];
                wv0[l].x = t0.x * inv0; wv0[l].y = t0.y * inv0;
                wv0[l].z = t0.z * inv0; wv0[l].w = t0.w * inv0;
                wv1[l].x = t1.x * inv1; wv1[l].y = t1.y * inv1;
                wv1[l].z = t1.z * inv1; wv1[l].w = t1.w * inv1;
            }
            const long coff = hh * 32 + l16 * 2;
#pragma unroll
            for (int sub = 0; sub < 2; ++sub) {
                const int nd = (g & 15) + sub * 16 + ((g >> 4) << 5);
                float4 a0 = {0.f, 0.f, 0.f, 0.f}, a1 = {0.f, 0.f, 0.f, 0.f};
#pragma unroll
                for (int p = 0; p < N_PATHS; ++p) {
                    const int* ip = &idxs[nd * 64 + p * 8];
                    int4 i0 = *(const int4*)ip;
                    int4 i1 = *(const int4*)(ip + 4);
                    if (((tmask >> p) & 1u) == 0u) { GATH_FMA(wv0, a0); }
                    else                           { GATH_FMA(wv1, a1); }
                }
                uint2 o0, o1;
                o0.x = (uint)f2bf(a0.x) | ((uint)f2bf(a0.y) << 16);
                o0.y = (uint)f2bf(a0.z) | ((uint)f2bf(a0.w) << 16);
                o1.x = (uint)f2bf(a1.x) | ((uint)f2bf(a1.y) << 16);
                o1.y = (uint)f2bf(a1.z) | ((uint)f2bf(a1.w) << 16);
                int e0 = nd * 256 + hh * 64 + l16 * 4;        // type-0 half
                int e1 = e0 + 128;                            // type-1 half
                *(uint2*)&Pt[e0 ^ ((nd & 7) << 3)] = o0;
                *(uint2*)&Pt[e1 ^ ((nd & 7) << 3)] = o1;
            }
        }
#undef GATH_FMA
    }
    __syncthreads();    // idxs dead from here; Ws overlays it

    // ---- phase 2: GEMM 64x128, A = Pt (LDS-resident) ----
    const int lane = tid & 63;
    const int w = tid >> 6;                 // 0..7
    const int wr = w >> 2, wc = w & 3;      // 2 row-blocks x 4 col-blocks
    const int l15 = lane & 15, l4 = lane >> 4;

    f32x4 acc[2][2];
#pragma unroll
    for (int mr = 0; mr < 2; ++mr)
#pragma unroll
        for (int nc = 0; nc < 2; ++nc)
#pragma unroll
            for (int j = 0; j < 4; ++j) acc[mr][nc][j] = 0.f;

    for (int k0 = 0; k0 < 2 * HID; k0 += 64) {
        // stage W chunk [128][64] (2 granules/thread)
#pragma unroll
        for (int c = tid; c < 128 * 8; c += 512) {
            int r = c >> 3, kc = c & 7;
            bf16x8 v = *(const bf16x8*)(W + (long)r * (2 * HID) + k0 + kc * 8);
            int di = (r * 64 + kc * 8) ^ ((r & 7) << 3);
            *(bf16x8*)&Ws[di] = v;
        }
        __syncthreads();

#pragma unroll
        for (int ks = 0; ks < 2; ++ks) {
            const int kk = ks * 32 + l4 * 8;
            bf16x8 av[2], bv[2];
#pragma unroll
            for (int mr = 0; mr < 2; ++mr) {
                int rA = wr * 32 + mr * 16 + l15;
                av[mr] = *(const bf16x8*)&Pt[(rA * 256 + k0 + kk) ^ ((rA & 7) << 3)];
            }
#pragma unroll
            for (int nc = 0; nc < 2; ++nc) {
                int rB = wc * 32 + nc * 16 + l15;
                bv[nc] = *(const bf16x8*)&Ws[(rB * 64 + kk) ^ ((rB & 7) << 3)];
            }
#pragma unroll
            for (int mr = 0; mr < 2; ++mr)
#pragma unroll
                for (int nc = 0; nc < 2; ++nc)
                    acc[mr][nc] = __builtin_amdgcn_mfma_f32_16x16x32_bf16(
                        av[mr], bv[nc], acc[mr][nc], 0, 0, 0);
        }
        __syncthreads();
    }

    // ---- epilogue: residual mix ----
#pragma unroll
    for (int mr = 0; mr < 2; ++mr) {
#pragma unroll
        for (int nc = 0; nc < 2; ++nc) {
            int gn = wc * 32 + nc * 16 + l15;
#pragma unroll
            for (int j = 0; j < 4; ++j) {
                int gm = nbase + wr * 32 + mr * 16 + l4 * 4 + j;
                if (gm >= NN) continue;
                float v = fmaxf(acc[mr][nc][j], 0.f);
                v = 0.8f * v + 0.1f * bf2f(pre[(long)gm * HID + gn])
                             + 0.1f * bf2f(in0[(long)gm * HID + gn]);
                dst[(long)gm * HID + gn] = f2bf(v);
            }
        }
    }
}

// ---------------------------------------------------------------------------
extern "C" void kernel_launch(void* const* d_in, const int* in_sizes, int n_in,
                              void* d_out, int out_size, void* d_ws, size_t ws_size,
                              hipStream_t stream)
{
    const float* input_x      = (const float*)d_in[0];
    const int*   paths        = (const int*)d_in[1];
    const int*   path_types   = (const int*)d_in[2];
    const float* fc_in_w      = (const float*)d_in[3];
    const float* fc_in_b      = (const float*)d_in[4];
    const float* fc_out_w     = (const float*)d_in[5];
    const float* fc_out_b     = (const float*)d_in[6];
    const float* layer_fc_w   = (const float*)d_in[7];
    const float* path_weights = (const float*)d_in[8];
    float* out = (float*)d_out;

    char* p = (char*)d_ws;
    ushort* w_in     = (ushort*)p; p += HID * IN_DIM * 2;
    ushort* w_layer  = (ushort*)p; p += N_LAYERS * HID * N_TYPES * HID * 2;
    ushort* w_out    = (ushort*)p; p += OUT_DIM * HID * 2;
    ushort* in_feats = (ushort*)p; p += (long)NN * HID * 2;
    ushort* featsA   = (ushort*)p; p += (long)NN * HID * 2;
    ushort* featsB   = (ushort*)p; p += (long)NN * HID * 2;

    cvt_weights<<<168, 256, 0, stream>>>(fc_in_w, layer_fc_w, fc_out_w,
                                         w_in, w_layer, w_out);

    const int GG = (NN + 63) / 64;   // 313

    gemm_mfma<HID, IN_DIM, 0, true><<<GG, 256, 0, stream>>>(
        input_x, w_in, fc_in_b, in_feats, NN);

    const ushort* src = in_feats;
    ushort* dsts[N_LAYERS] = {featsA, featsB, featsA, featsB};
    for (int i = 0; i < N_LAYERS; ++i) {
        fused_layer<<<GG, 512, 0, stream>>>(
            (const uint*)src, paths, path_types,
            path_weights + (long)i * N_TYPES * PATH_LEN * HID,
            w_layer + (long)i * HID * N_TYPES * HID,
            src, in_feats, dsts[i]);
        src = dsts[i];
    }

    gemm_mfma<OUT_DIM, HID, 2, false><<<GG, 256, 0, stream>>>(
        src, w_out, fc_out_b, out, NN);
}

// Round 7
// 210.919 us; speedup vs baseline: 1.4757x; 1.4757x over previous
//
#include <hip/hip_runtime.h>

#define NN 20000
#define IN_DIM 256
#define HID 128
#define OUT_DIM 64
#define N_LAYERS 4
#define N_PATHS 8
#define PATH_LEN 8
#define N_TYPES 2

typedef __attribute__((ext_vector_type(8))) short bf16x8;
typedef __attribute__((ext_vector_type(4))) float f32x4;

__device__ __forceinline__ float bf2f(ushort u) {
    union { uint u; float f; } c; c.u = ((uint)u) << 16; return c.f;
}
__device__ __forceinline__ ushort f2bf(float f) {
    union { float f; uint u; } c; c.f = f;
    uint u = c.u;
    uint lsb = (u >> 16) & 1;
    u += 0x7fffu + lsb;          // round-to-nearest-even (inputs finite)
    return (ushort)(u >> 16);
}

// ---------------------------------------------------------------------------
// One-shot fp32 -> bf16 conversion of all weight matrices (quad-per-thread).
// ---------------------------------------------------------------------------
__global__ __launch_bounds__(256) void cvt_weights(
    const float* __restrict__ w_in, const float* __restrict__ w_layer,
    const float* __restrict__ w_out,
    ushort* __restrict__ o_in, ushort* __restrict__ o_layer,
    ushort* __restrict__ o_out)
{
    int i = blockIdx.x * 256 + threadIdx.x;
    const float* s; ushort* d; int off;
    if (i < 8192)        { s = w_in;    d = o_in;    off = i; }
    else if (i < 40960)  { s = w_layer; d = o_layer; off = i - 8192; }
    else if (i < 43008)  { s = w_out;   d = o_out;   off = i - 40960; }
    else return;
    float4 v = ((const float4*)s)[off];
    ushort4 o;
    o.x = f2bf(v.x); o.y = f2bf(v.y); o.z = f2bf(v.z); o.w = f2bf(v.w);
    ((ushort4*)d)[off] = o;
}

// ---------------------------------------------------------------------------
// bf16 MFMA GEMM: C = epilogue(A[M,K] @ W[N,K]^T), fp32 accumulate.
// BM=64, BK=64, 4 waves (2x2), wave computes 32 x N/2. MFMA 16x16x32 bf16.
// LDS XOR-swizzle on 16B granules: elem ^= (row&7)<<3 (T2, conflict-free).
// AF32: A operand is fp32 in global, converted to bf16 while staging.
// EPI 0: bf16 out = relu(acc + bias[n])
// EPI 1: bf16 out = 0.8*relu(acc) + 0.1*pre + 0.1*in0
// EPI 2: f32  out = relu(acc + bias[n])
// ---------------------------------------------------------------------------
template <int N, int K, int EPI, bool AF32>
__global__ __launch_bounds__(256) void gemm_mfma(
    const void* __restrict__ Ap,
    const ushort* __restrict__ W,     // [N][K] bf16
    const float* __restrict__ bias,
    const ushort* __restrict__ pre,
    const ushort* __restrict__ in0,
    void* __restrict__ Cout,
    int M)
{
    constexpr int BM = 64, BK = 64;
    constexpr int NC = N / 32;              // 4 (N=128) or 2 (N=64)

    __shared__ short As[BM * BK];
    __shared__ short Ws[N * BK];

    const int tid = threadIdx.x;
    const int lane = tid & 63;
    const int w = tid >> 6;
    const int wr = w >> 1, wc = w & 1;
    const int m0 = blockIdx.x * BM;
    const int l15 = lane & 15, l4 = lane >> 4;

    f32x4 acc[2][NC];
#pragma unroll
    for (int mr = 0; mr < 2; ++mr)
#pragma unroll
        for (int nc = 0; nc < NC; ++nc)
#pragma unroll
            for (int j = 0; j < 4; ++j) acc[mr][nc][j] = 0.f;

    for (int k0 = 0; k0 < K; k0 += BK) {
        // ---- stage A tile ----
#pragma unroll
        for (int c = tid; c < BM * BK / 8; c += 256) {
            int r = c >> 3, kc = c & 7;
            int gr = m0 + r; if (gr >= M) gr = M - 1;   // clamp tail
            bf16x8 v;
            if constexpr (AF32) {
                const float* Af = (const float*)Ap;
                float4 v0 = *(const float4*)(Af + (long)gr * K + k0 + kc * 8);
                float4 v1 = *(const float4*)(Af + (long)gr * K + k0 + kc * 8 + 4);
                v[0] = (short)f2bf(v0.x); v[1] = (short)f2bf(v0.y);
                v[2] = (short)f2bf(v0.z); v[3] = (short)f2bf(v0.w);
                v[4] = (short)f2bf(v1.x); v[5] = (short)f2bf(v1.y);
                v[6] = (short)f2bf(v1.z); v[7] = (short)f2bf(v1.w);
            } else {
                v = *(const bf16x8*)((const ushort*)Ap + (long)gr * K + k0 + kc * 8);
            }
            int di = (r * BK + kc * 8) ^ ((r & 7) << 3);
            *(bf16x8*)&As[di] = v;
        }
        // ---- stage W tile (bf16) ----
#pragma unroll
        for (int c = tid; c < N * BK / 8; c += 256) {
            int r = c >> 3, kc = c & 7;
            bf16x8 v = *(const bf16x8*)(W + (long)r * K + k0 + kc * 8);
            int di = (r * BK + kc * 8) ^ ((r & 7) << 3);
            *(bf16x8*)&Ws[di] = v;
        }
        __syncthreads();

#pragma unroll
        for (int ks = 0; ks < 2; ++ks) {
            bf16x8 av[2], bv[NC];
            const int kk = ks * 32 + l4 * 8;
#pragma unroll
            for (int mr = 0; mr < 2; ++mr) {
                int r = wr * 32 + mr * 16 + l15;
                av[mr] = *(const bf16x8*)&As[(r * BK + kk) ^ ((r & 7) << 3)];
            }
#pragma unroll
            for (int nc = 0; nc < NC; ++nc) {
                int r = wc * (N / 2) + nc * 16 + l15;
                bv[nc] = *(const bf16x8*)&Ws[(r * BK + kk) ^ ((r & 7) << 3)];
            }
#pragma unroll
            for (int mr = 0; mr < 2; ++mr)
#pragma unroll
                for (int nc = 0; nc < NC; ++nc)
                    acc[mr][nc] = __builtin_amdgcn_mfma_f32_16x16x32_bf16(
                        av[mr], bv[nc], acc[mr][nc], 0, 0, 0);
        }
        __syncthreads();
    }

#pragma unroll
    for (int mr = 0; mr < 2; ++mr) {
#pragma unroll
        for (int nc = 0; nc < NC; ++nc) {
            int gn = wc * (N / 2) + nc * 16 + l15;
#pragma unroll
            for (int j = 0; j < 4; ++j) {
                int gm = m0 + wr * 32 + mr * 16 + l4 * 4 + j;
                if (gm >= M) continue;
                float v = acc[mr][nc][j];
                if (EPI == 0) {
                    v += bias[gn];
                    v = fmaxf(v, 0.f);
                    ((ushort*)Cout)[(long)gm * N + gn] = f2bf(v);
                } else if (EPI == 1) {
                    v = fmaxf(v, 0.f);
                    v = 0.8f * v + 0.1f * bf2f(pre[(long)gm * N + gn])
                                 + 0.1f * bf2f(in0[(long)gm * N + gn]);
                    ((ushort*)Cout)[(long)gm * N + gn] = f2bf(v);
                } else {
                    v += bias[gn];
                    v = fmaxf(v, 0.f);
                    ((float*)Cout)[(long)gm * N + gn] = v;
                }
            }
        }
    }
}

// ---------------------------------------------------------------------------
// Gather + unweighted path-sum per (type,l) + weighted combine.
// TEMPORAL h-halving for L2 residency: grid = [1250 tiles x half 0] then
// [1250 tiles x half 1]. While half-0 blocks run, every XCD's L2 holds only
// the 2.56 MB feats half (fits 4 MiB) -> gather reads become L2 hits.
// Block = 256 thr = 16 nodes x 16 lanes; lane owns 4 channels (uint2 = 8B).
// Type handling via bitmask+popcount (no runtime-indexed reg arrays).
// ---------------------------------------------------------------------------
__global__ __launch_bounds__(256) void gather_bf16(
    const uint* __restrict__ feats_u,   // [NN][64]  (bf16x2 packed)
    const int* __restrict__ paths,      // [P][NN][L]
    const int* __restrict__ ptypes,     // [P]
    const float* __restrict__ pw,       // [2][L][HID] f32
    uint* __restrict__ fout_u)          // [NN][128] (bf16x2 packed)
{
    const int gb = (int)blockIdx.x;
    const int h_half = gb / (NN / 16);  // 0: first 1250 blocks, 1: rest
    const int ntile = gb % (NN / 16);
    const int nbase = ntile * 16;

    const int tid = threadIdx.x;
    const int node = tid >> 4;          // 0..15
    const int l16 = tid & 15;           // channel quad within the h-half
    const int n = nbase + node;

    __shared__ int idx_l[16][N_TYPES][PATH_LEN][8];

    // type bitmask (bit p = type of path p), counts via popcount
    uint tmask = 0;
#pragma unroll
    for (int p = 0; p < N_PATHS; ++p) tmask |= (uint)(ptypes[p] != 0) << p;
    const int cnt1 = __popc(tmask);
    const int cnt0 = N_PATHS - cnt1;

    // stage 16 nodes x 64 indices, sorted by (type, l, rank)
#pragma unroll
    for (int j = 0; j < 4; ++j) {
        int li = tid * 4 + j;           // 0..1023
        int nd = li >> 6, k = li & 63, p = k >> 3, l = k & 7;
        int tp = (int)((tmask >> p) & 1u);
        uint below = tmask & ((1u << p) - 1u);
        int rank = tp ? __popc(below) : p - __popc(below);
        idx_l[nd][tp][l][rank] = paths[((long)p * NN + nbase + nd) * PATH_LEN + l];
    }
    __syncthreads();

    const float inv0 = cnt0 ? 1.f / (float)cnt0 : 0.f;
    const float inv1 = cnt1 ? 1.f / (float)cnt1 : 0.f;

    // per-lane weights for both types, pre-scaled by 1/count (static arrays)
    float4 wv[2][PATH_LEN];
#pragma unroll
    for (int e = 0; e < 2; ++e) {
        float s = e ? inv1 : inv0;
#pragma unroll
        for (int l = 0; l < PATH_LEN; ++l) {
            float4 t = *(const float4*)&pw[(e * PATH_LEN + l) * HID + h_half * 64 + l16 * 4];
            wv[e][l].x = t.x * s; wv[e][l].y = t.y * s;
            wv[e][l].z = t.z * s; wv[e][l].w = t.w * s;
        }
    }

    const long coff = h_half * 32 + l16 * 2;   // uint offset within a row
    float4 acc[2];
#pragma unroll
    for (int e = 0; e < 2; ++e) {
        acc[e].x = acc[e].y = acc[e].z = acc[e].w = 0.f;
        const int ce = e ? cnt1 : cnt0;
        if (ce == 4) {
#pragma unroll
            for (int l = 0; l < PATH_LEN; ++l) {
                int4 r4 = *(const int4*)&idx_l[node][e][l][0];
                uint2 v0 = *(const uint2*)(feats_u + (long)r4.x * 64 + coff);
                uint2 v1 = *(const uint2*)(feats_u + (long)r4.y * 64 + coff);
                uint2 v2 = *(const uint2*)(feats_u + (long)r4.z * 64 + coff);
                uint2 v3 = *(const uint2*)(feats_u + (long)r4.w * 64 + coff);
                float sx = bf2f((ushort)(v0.x & 0xffff)) + bf2f((ushort)(v1.x & 0xffff))
                         + bf2f((ushort)(v2.x & 0xffff)) + bf2f((ushort)(v3.x & 0xffff));
                float sy = bf2f((ushort)(v0.x >> 16)) + bf2f((ushort)(v1.x >> 16))
                         + bf2f((ushort)(v2.x >> 16)) + bf2f((ushort)(v3.x >> 16));
                float sz = bf2f((ushort)(v0.y & 0xffff)) + bf2f((ushort)(v1.y & 0xffff))
                         + bf2f((ushort)(v2.y & 0xffff)) + bf2f((ushort)(v3.y & 0xffff));
                float sw = bf2f((ushort)(v0.y >> 16)) + bf2f((ushort)(v1.y >> 16))
                         + bf2f((ushort)(v2.y >> 16)) + bf2f((ushort)(v3.y >> 16));
                acc[e].x += sx * wv[e][l].x;
                acc[e].y += sy * wv[e][l].y;
                acc[e].z += sz * wv[e][l].z;
                acc[e].w += sw * wv[e][l].w;
            }
        } else {
            // generic fallback for any type distribution
#pragma unroll
            for (int l = 0; l < PATH_LEN; ++l) {
                float sx = 0.f, sy = 0.f, sz = 0.f, sw = 0.f;
                for (int q = 0; q < ce; ++q) {
                    int row = idx_l[node][e][l][q];
                    uint2 v = *(const uint2*)(feats_u + (long)row * 64 + coff);
                    sx += bf2f((ushort)(v.x & 0xffff));
                    sy += bf2f((ushort)(v.x >> 16));
                    sz += bf2f((ushort)(v.y & 0xffff));
                    sw += bf2f((ushort)(v.y >> 16));
                }
                acc[e].x += sx * wv[e][l].x;
                acc[e].y += sy * wv[e][l].y;
                acc[e].z += sz * wv[e][l].z;
                acc[e].w += sw * wv[e][l].w;
            }
        }
    }

#pragma unroll
    for (int e = 0; e < 2; ++e) {
        uint2 o;
        o.x = (uint)f2bf(acc[e].x) | ((uint)f2bf(acc[e].y) << 16);
        o.y = (uint)f2bf(acc[e].z) | ((uint)f2bf(acc[e].w) << 16);
        *(uint2*)(fout_u + (long)n * 128 + e * 64 + coff) = o;
    }
}

// ---------------------------------------------------------------------------
extern "C" void kernel_launch(void* const* d_in, const int* in_sizes, int n_in,
                              void* d_out, int out_size, void* d_ws, size_t ws_size,
                              hipStream_t stream)
{
    const float* input_x      = (const float*)d_in[0];
    const int*   paths        = (const int*)d_in[1];
    const int*   path_types   = (const int*)d_in[2];
    const float* fc_in_w      = (const float*)d_in[3];
    const float* fc_in_b      = (const float*)d_in[4];
    const float* fc_out_w     = (const float*)d_in[5];
    const float* fc_out_b     = (const float*)d_in[6];
    const float* layer_fc_w   = (const float*)d_in[7];
    const float* path_weights = (const float*)d_in[8];
    float* out = (float*)d_out;

    char* p = (char*)d_ws;
    ushort* w_in     = (ushort*)p; p += HID * IN_DIM * 2;                   // 64 KB
    ushort* w_layer  = (ushort*)p; p += N_LAYERS * HID * N_TYPES * HID * 2; // 256 KB
    ushort* w_out    = (ushort*)p; p += OUT_DIM * HID * 2;                  // 16 KB
    ushort* in_feats = (ushort*)p; p += (long)NN * HID * 2;                 // 5.12 MB
    ushort* featsA   = (ushort*)p; p += (long)NN * HID * 2;
    ushort* featsB   = (ushort*)p; p += (long)NN * HID * 2;
    ushort* fout     = (ushort*)p; p += (long)NN * N_TYPES * HID * 2;       // 10.24 MB

    cvt_weights<<<168, 256, 0, stream>>>(fc_in_w, layer_fc_w, fc_out_w,
                                         w_in, w_layer, w_out);

    const int GG = (NN + 63) / 64;          // 313
    const int GATHER_GRID = (NN / 16) * 2;  // 2500: halves sequential

    gemm_mfma<HID, IN_DIM, 0, true><<<GG, 256, 0, stream>>>(
        input_x, w_in, fc_in_b, nullptr, nullptr, in_feats, NN);

    const ushort* src = in_feats;
    ushort* dsts[N_LAYERS] = {featsA, featsB, featsA, featsB};
    for (int i = 0; i < N_LAYERS; ++i) {
        gather_bf16<<<GATHER_GRID, 256, 0, stream>>>(
            (const uint*)src, paths, path_types,
            path_weights + (long)i * N_TYPES * PATH_LEN * HID, (uint*)fout);
        gemm_mfma<HID, N_TYPES * HID, 1, false><<<GG, 256, 0, stream>>>(
            fout, w_layer + (long)i * HID * N_TYPES * HID, nullptr,
            src, in_feats, dsts[i], NN);
        src = dsts[i];
    }

    gemm_mfma<OUT_DIM, HID, 2, false><<<GG, 256, 0, stream>>>(
        src, w_out, fc_out_b, nullptr, nullptr, out, NN);
}